// Round 9
// baseline (218.767 us; speedup 1.0000x reference)
//
#include <hip/hip_runtime.h>
#include <hip/hip_bf16.h>
#include <stdint.h>

typedef __attribute__((ext_vector_type(8))) short bf16x8;
typedef __attribute__((ext_vector_type(4))) float f32x4;
typedef __attribute__((ext_vector_type(4))) unsigned short u16x4;

#define B_ 4
#define T_ 2048
#define C_ 1024
#define H_ 16
#define D_ 64

// round-to-nearest-even fp32 -> bf16
__device__ __forceinline__ unsigned short f2bf(float f) {
  union { float f; uint32_t u; } v; v.f = f;
  uint32_t u = v.u;
  uint32_t r = (u + 0x7FFFu + ((u >> 16) & 1u)) >> 16;
  return (unsigned short)r;
}

// fused cast of all three fp32 inputs -> bf16 (one launch instead of three)
__global__ void __launch_bounds__(256) cast_all(const float* __restrict__ x,
                                                const float* __restrict__ wqkv,
                                                const float* __restrict__ wout,
                                                unsigned short* __restrict__ xb,
                                                unsigned short* __restrict__ wqkvb,
                                                unsigned short* __restrict__ woutb) {
  int bid = blockIdx.x;
  const float* src; unsigned short* dst; int i;
  if (bid < 8192)       { src = x;    dst = xb;    i = bid * 256 + threadIdx.x; }
  else if (bid < 11264) { src = wqkv; dst = wqkvb; i = (bid - 8192) * 256 + threadIdx.x; }
  else                  { src = wout; dst = woutb; i = (bid - 11264) * 256 + threadIdx.x; }
  float4 f = ((const float4*)src)[i];
  u16x4 o;
  o[0] = f2bf(f.x); o[1] = f2bf(f.y); o[2] = f2bf(f.z); o[3] = f2bf(f.w);
  ((u16x4*)dst)[i] = o;
}

// ---------------------------------------------------------------------------
// QKV GEMM, 8-phase-style counted-vmcnt schedule (T3+T4+T5).
// C[8192,3072] = A[8192,1024] * W[3072,1024]^T, bf16, fp32 acc.
// 256x256 tile, BK=32, 512 thr = 8 waves (2 wr x 4 wc), per-wave 128x64
// (acc[8][4]). LDS: 4-slot ring, slot = A[256x32] + B[256x32] = 32 KB,
// total 128 KB. Staging runs TWO K-tiles ahead (A-set at p0, B-set at p1 of
// tile t stage tile t+2). Counted wait: ONE s_waitcnt vmcnt(6) per tile at
// p0 (6 = 3 in-flight sets x 2 loads/thread: A(t+1),B(t+1),A(t+2)); never
// drains in the main loop (peeled: t=30 -> vmcnt(4), t=31 -> vmcnt(0)).
// Correctness: per-wave vmcnt + s_barrier join => all waves' DMA for tile t
// landed before any p0 ds_read; slot (t+2)&3 restaged at tile t was last
// read at tile t-2, >=2 barriers earlier (each phase ends with lgkmcnt(0)
// before MFMA and a barrier opens the next phase). Raw s_barrier + asm
// waitcnt + sched_barrier(0) fences (rule: hipcc hoists MFMA past asm
// lgkmcnt without the sched_barrier). setprio(1) around each 16-MFMA cluster
// (T5 pays only with this phase role-split). Epilogue: Q/K -> LDS [128][264]
// transpose (2 half-passes) -> coalesced 16B scatter; V -> packed u16x4 to
// vt[B,H,D,T].
// ---------------------------------------------------------------------------
__global__ void __launch_bounds__(512, 2) gemm_qkv8(const unsigned short* __restrict__ A,
                                                    const unsigned short* __restrict__ Bm,
                                                    unsigned short* __restrict__ qb,
                                                    unsigned short* __restrict__ kb,
                                                    unsigned short* __restrict__ vb) {
  __shared__ short lds[65536];  // 128 KB ring; epilogue reuses [128][264]
  const int tid = threadIdx.x;
  const int bm = blockIdx.y * 256;
  const int bn = blockIdx.x * 256;
  const int wave = tid >> 6;
  const int l = tid & 63;
  const int wr = wave >> 2;        // 0..1  (m half: 128 rows)
  const int wc = wave & 3;         // 0..3  (n quarter: 64 cols)
  const int lm = l & 15, lq = l >> 4;

  f32x4 acc[8][4];
#pragma unroll
  for (int i = 0; i < 8; i++)
#pragma unroll
    for (int j = 0; j < 4; j++) acc[i][j] = (f32x4){0.f, 0.f, 0.f, 0.f};

  // staging: per set (A or B of one K-tile) = 256 rows x 32 cols x 2B = 16 KB
  // = 1024 x 16B chunks = 512 thr x 2 loads. chunk c = i*512+tid:
  // row = c>>2, colchunk = c&3. dest linear c*16 B (per (i,wave): contiguous
  // 1 KB, wave-uniform base + lane*16 as gload_lds requires).
  const unsigned short* gA[2];
  const unsigned short* gB[2];
  int dA[2], dB[2];
#pragma unroll
  for (int i = 0; i < 2; i++) {
    int c = i * 512 + tid;
    gA[i] = A + (size_t)(bm + (c >> 2)) * 1024 + (c & 3) * 8;
    gB[i] = Bm + (size_t)(bn + (c >> 2)) * 1024 + (c & 3) * 8;
    dA[i] = c * 8;           // shorts within slot
    dB[i] = 8192 + c * 8;
  }

#define STA(t)                                                                   \
  do {                                                                           \
    _Pragma("unroll")                                                            \
    for (int i = 0; i < 2; i++)                                                  \
      __builtin_amdgcn_global_load_lds(                                          \
          (__attribute__((address_space(1))) void*)(uintptr_t)(const void*)(gA[i] + (t) * 32), \
          (__attribute__((address_space(3))) void*)(lds + ((t) & 3) * 16384 + dA[i]),          \
          16, 0, 0);                                                             \
  } while (0)
#define STB(t)                                                                   \
  do {                                                                           \
    _Pragma("unroll")                                                            \
    for (int i = 0; i < 2; i++)                                                  \
      __builtin_amdgcn_global_load_lds(                                          \
          (__attribute__((address_space(1))) void*)(uintptr_t)(const void*)(gB[i] + (t) * 32), \
          (__attribute__((address_space(3))) void*)(lds + ((t) & 3) * 16384 + dB[i]),          \
          16, 0, 0);                                                             \
  } while (0)
#define FENCE() __builtin_amdgcn_sched_barrier(0)

  // prologue: stage tiles 0 and 1 (4 sets, 8 loads/thread)
  STA(0); STB(0); STA(1); STB(1);
  FENCE();

  for (int t = 0; t < 32; ++t) {
    const short* Sa = lds + (t & 3) * 16384;
    const short* Sb = Sa + 8192;
    // ---- phase 0: stage A(t+2) | wait tile t | frags A(all)+B(n 0,1) | 16 MFMA
    if (t + 2 < 32) STA(t + 2);
    FENCE();
    if (t <= 29)      asm volatile("s_waitcnt vmcnt(6)" ::: "memory");
    else if (t == 30) asm volatile("s_waitcnt vmcnt(4)" ::: "memory");
    else              asm volatile("s_waitcnt vmcnt(0)" ::: "memory");
    __builtin_amdgcn_s_barrier();
    FENCE();
    bf16x8 Af[8], Bf[2];
#pragma unroll
    for (int mi = 0; mi < 8; mi++)
      Af[mi] = *(const bf16x8*)&Sa[(wr * 128 + 16 * mi + lm) * 32 + 8 * lq];
#pragma unroll
    for (int nj = 0; nj < 2; nj++)
      Bf[nj] = *(const bf16x8*)&Sb[(wc * 64 + 16 * nj + lm) * 32 + 8 * lq];
    asm volatile("s_waitcnt lgkmcnt(0)" ::: "memory");
    FENCE();
    __builtin_amdgcn_s_setprio(1);
#pragma unroll
    for (int mi = 0; mi < 8; mi++)
#pragma unroll
      for (int nj = 0; nj < 2; nj++)
        acc[mi][nj] = __builtin_amdgcn_mfma_f32_16x16x32_bf16(Af[mi], Bf[nj], acc[mi][nj], 0, 0, 0);
    __builtin_amdgcn_s_setprio(0);
    FENCE();
    // ---- phase 1: stage B(t+2) | barrier | frags B(n 2,3) | 16 MFMA
    if (t + 2 < 32) STB(t + 2);
    FENCE();
    __builtin_amdgcn_s_barrier();
    FENCE();
    bf16x8 Bg[2];
#pragma unroll
    for (int nj = 0; nj < 2; nj++)
      Bg[nj] = *(const bf16x8*)&Sb[(wc * 64 + 16 * (nj + 2) + lm) * 32 + 8 * lq];
    asm volatile("s_waitcnt lgkmcnt(0)" ::: "memory");
    FENCE();
    __builtin_amdgcn_s_setprio(1);
#pragma unroll
    for (int mi = 0; mi < 8; mi++)
#pragma unroll
      for (int nj = 0; nj < 2; nj++)
        acc[mi][2 + nj] = __builtin_amdgcn_mfma_f32_16x16x32_bf16(Af[mi], Bg[nj], acc[mi][2 + nj], 0, 0, 0);
    __builtin_amdgcn_s_setprio(0);
    FENCE();
  }
#undef STA
#undef STB

  // C/D layout: col = lane&15, row = (lane>>4)*4 + reg  [measured m89/m91]
  if (bn >= 2048) {
    // V block: store TRANSPOSED vt[b,h,d,t]; acc[.][.][0..3] = 4 consecutive t.
#pragma unroll
    for (int mi = 0; mi < 8; mi++)
#pragma unroll
      for (int nj = 0; nj < 4; nj++) {
        int m0 = bm + wr * 128 + 16 * mi + 4 * lq;        // t base (4-aligned)
        int n = (bn - 2048) + wc * 64 + 16 * nj + lm;     // 0..1023
        int hh = n >> 6, d = n & 63;
        int b = m0 >> 11, tt = m0 & 2047;
        u16x4 o;
#pragma unroll
        for (int r = 0; r < 4; r++) o[r] = f2bf(acc[mi][nj][r]);
        *(u16x4*)&vb[(((size_t)(b * 16 + hh)) * 64 + d) * 2048 + tt] = o;
      }
  } else {
    // Q/K block: LDS [128][264] transpose in two half-passes -> 16B scatter
#pragma unroll
    for (int p = 0; p < 2; ++p) {
      __syncthreads();   // p=0: main loop done (vmcnt drained at t=31); p=1: pass-0 reads done
      if (wr == p) {
#pragma unroll
        for (int mi = 0; mi < 8; mi++)
#pragma unroll
          for (int nj = 0; nj < 4; nj++)
#pragma unroll
            for (int r = 0; r < 4; r++)
              lds[(16 * mi + 4 * lq + r) * 264 + wc * 64 + 16 * nj + lm] =
                  (short)f2bf(acc[mi][nj][r]);
      }
      __syncthreads();
#pragma unroll
      for (int k = 0; k < 8; k++) {
        int c = tid + 512 * k;       // 4096 chunks of 8 shorts (128 x 256)
        int row = c >> 5;            // 0..127
        int col = (c & 31) << 3;     // 0..248
        bf16x8 v = *(const bf16x8*)&lds[row * 264 + col];
        int m = bm + 128 * p + row, n = bn + col;
        int which = n >> 10, rem = n & 1023;
        int hh = rem >> 6, d = rem & 63;     // d 8-aligned, within one head
        int b = m >> 11, tt = m & 2047;
        unsigned short* dst = (which == 0) ? qb : kb;
        *(bf16x8*)&dst[(((size_t)(b * 16 + hh)) * 2048 + tt) * 64 + d] = v;
      }
    }
  }
#undef FENCE
}

// ---------------------------------------------------------------------------
// Out-proj GEMM: C[8192,1024] = A[8192,1024] * W[1024,1024]^T, fp32 out.
// 128x128 tile, BK=32, 2-phase dbuf (proven round-3 structure).
// ---------------------------------------------------------------------------
__global__ void __launch_bounds__(256) gemm_out(const unsigned short* __restrict__ A,
                                                const unsigned short* __restrict__ Bm,
                                                float* __restrict__ fo) {
  __shared__ short lds[16384];
  const int tid = threadIdx.x;
  const int bm = blockIdx.y * 128;
  const int bn = blockIdx.x * 128;
  const int wave = tid >> 6;
  const int l = tid & 63;
  const int wm = wave >> 1, wn = wave & 1;
  const int lm = l & 15, lq = l >> 4;
  const int lr = l >> 2;
  const int lc = (l & 3) << 3;

  f32x4 acc[4][4];
#pragma unroll
  for (int i = 0; i < 4; i++)
#pragma unroll
    for (int j = 0; j < 4; j++) acc[i][j] = (f32x4){0.f, 0.f, 0.f, 0.f};

  const unsigned short* gsrc[4];
  int ldoff[4];
#pragma unroll
  for (int i = 0; i < 4; i++) {
    int c = wave * 4 + i;
    if (c < 8) {
      gsrc[i] = A + (size_t)(bm + 16 * c + lr) * 1024 + lc;
      ldoff[i] = (16 * c) * 32;
    } else {
      gsrc[i] = Bm + (size_t)(bn + 16 * (c - 8) + lr) * 1024 + lc;
      ldoff[i] = 8192 + (16 * (c - 8)) * 32;
    }
  }

#define STAGE(curb, kk)                                                          \
  do {                                                                           \
    _Pragma("unroll")                                                            \
    for (int i = 0; i < 4; i++) {                                                \
      __builtin_amdgcn_global_load_lds(                                          \
          (__attribute__((address_space(1))) void*)(uintptr_t)(const void*)(gsrc[i] + (kk)), \
          (__attribute__((address_space(3))) void*)(lds + ldoff[i] + (curb) * 4096),         \
          16, 0, 0);                                                             \
    }                                                                            \
  } while (0)

  STAGE(0, 0);
  int cur = 0;
  __syncthreads();

  for (int k0 = 0; k0 < 1024; k0 += 32) {
    if (k0 + 32 < 1024) STAGE(cur ^ 1, k0 + 32);
    bf16x8 af[4], bfr[4];
#pragma unroll
    for (int i = 0; i < 4; i++)
      af[i] = *(const bf16x8*)&lds[cur * 4096 + (wm * 64 + 16 * i + lm) * 32 + 8 * lq];
#pragma unroll
    for (int j = 0; j < 4; j++)
      bfr[j] = *(const bf16x8*)&lds[8192 + cur * 4096 + (wn * 64 + 16 * j + lm) * 32 + 8 * lq];
#pragma unroll
    for (int i = 0; i < 4; i++)
#pragma unroll
      for (int j = 0; j < 4; j++)
        acc[i][j] = __builtin_amdgcn_mfma_f32_16x16x32_bf16(af[i], bfr[j], acc[i][j], 0, 0, 0);
    __syncthreads();
    cur ^= 1;
  }
#undef STAGE

#pragma unroll
  for (int i = 0; i < 4; i++)
#pragma unroll
    for (int j = 0; j < 4; j++)
#pragma unroll
      for (int r = 0; r < 4; r++) {
        int m = bm + wm * 64 + 16 * i + 4 * lq + r;
        int n = bn + wn * 64 + 16 * j + lm;
        fo[(size_t)m * 1024 + n] = acc[i][j][r];
      }
}

// ---------------------------------------------------------------------------
// Sliding-window causal flash attention, SWAPPED-QK^T lane-local softmax.
// (unchanged from round 8 -- measured win)
// ---------------------------------------------------------------------------
__global__ void __launch_bounds__(256, 4) attn_swa(const unsigned short* __restrict__ Qb,
                                                   const unsigned short* __restrict__ Kb,
                                                   const unsigned short* __restrict__ Vt,
                                                   unsigned short* __restrict__ Ob) {
  __shared__ short P[4][16 * 48];  // per-wave P[q=16][k=32], row stride 48
  const int wv = threadIdx.x >> 6;
  const int l = threadIdx.x & 63;
  const int wid = blockIdx.x * 4 + wv;   // 0..4095
  const int bh = wid >> 6;               // 64 32-row q-groups per (b,h)
  const int t0 = (wid & 63) << 5;
  const int lm = l & 15, lq = l >> 4;
  const size_t base = (size_t)bh * (T_ * D_);

  bf16x8 qf[2][2];
#pragma unroll
  for (int qt = 0; qt < 2; qt++) {
    qf[qt][0] = *(const bf16x8*)(Qb + base + (size_t)(t0 + 16 * qt + lm) * 64 + 8 * lq);
    qf[qt][1] = *(const bf16x8*)(Qb + base + (size_t)(t0 + 16 * qt + lm) * 64 + 32 + 8 * lq);
  }

  float mst[2] = {-1e30f, -1e30f}, lst[2] = {0.f, 0.f};
  f32x4 Oa[2][4];
#pragma unroll
  for (int qt = 0; qt < 2; qt++)
#pragma unroll
    for (int jt = 0; jt < 4; jt++) Oa[qt][jt] = (f32x4){0.f, 0.f, 0.f, 0.f};

  const float cs = 0.125f * 1.44269504f;  // scale * log2(e)
  int jstart = t0 - 128; if (jstart < 0) jstart = 0;

  for (int j0 = jstart; j0 < t0 + 32; j0 += 32) {
    bf16x8 ka[2][2];
#pragma unroll
    for (int hh = 0; hh < 2; hh++) {
      int kr = j0 + 16 * hh + lm;
      ka[hh][0] = *(const bf16x8*)(Kb + base + (size_t)kr * 64 + 8 * lq);
      ka[hh][1] = *(const bf16x8*)(Kb + base + (size_t)kr * 64 + 32 + 8 * lq);
    }
    bf16x8 vf[4];
#pragma unroll
    for (int jt = 0; jt < 4; jt++)
      vf[jt] = *(const bf16x8*)(Vt + base + (size_t)(16 * jt + lm) * 2048 + j0 + 8 * lq);

#pragma unroll
    for (int qt = 0; qt < 2; qt++) {
      const int t0q = t0 + 16 * qt;
      const int t = t0q + lm;
      f32x4 s0 = (f32x4){0.f, 0.f, 0.f, 0.f}, s1 = (f32x4){0.f, 0.f, 0.f, 0.f};
      s0 = __builtin_amdgcn_mfma_f32_16x16x32_bf16(ka[0][0], qf[qt][0], s0, 0, 0, 0);
      s0 = __builtin_amdgcn_mfma_f32_16x16x32_bf16(ka[0][1], qf[qt][1], s0, 0, 0, 0);
      s1 = __builtin_amdgcn_mfma_f32_16x16x32_bf16(ka[1][0], qf[qt][0], s1, 0, 0, 0);
      s1 = __builtin_amdgcn_mfma_f32_16x16x32_bf16(ka[1][1], qf[qt][1], s1, 0, 0, 0);
      float sv[8];
      float m2 = -1e30f;
#pragma unroll
      for (int hh = 0; hh < 2; hh++)
#pragma unroll
        for (int r = 0; r < 4; r++) {
          int k = j0 + 16 * hh + 4 * lq + r;
          float x = (hh ? s1[r] : s0[r]) * cs;
          bool okm = (k <= t) && (k + 128 >= t);
          sv[hh * 4 + r] = okm ? x : -1e30f;
          m2 = fmaxf(m2, sv[hh * 4 + r]);
        }
      m2 = fmaxf(m2, __shfl_xor(m2, 16));
      m2 = fmaxf(m2, __shfl_xor(m2, 32));
      float mn = fmaxf(mst[qt], m2);
      float a = __builtin_amdgcn_exp2f(mst[qt] - mn);
      float ps = 0.f;
#pragma unroll
      for (int i = 0; i < 8; i++) {
        sv[i] = (sv[i] > -1e29f) ? __builtin_amdgcn_exp2f(sv[i] - mn) : 0.f;
        ps += sv[i];
      }
      ps += __shfl_xor(ps, 16);
      ps += __shfl_xor(ps, 32);
      lst[qt] = lst[qt] * a + ps;
      mst[qt] = mn;
#pragma unroll
      for (int hh = 0; hh < 2; hh++) {
        u16x4 pk;
#pragma unroll
        for (int r = 0; r < 4; r++) pk[r] = f2bf(sv[hh * 4 + r]);
        *(u16x4*)&P[wv][lm * 48 + 16 * hh + 4 * lq] = pk;
      }
      float al[4];
#pragma unroll
      for (int r = 0; r < 4; r++) al[r] = __shfl(a, 4 * lq + r);
#pragma unroll
      for (int jt = 0; jt < 4; jt++)
#pragma unroll
        for (int r = 0; r < 4; r++) Oa[qt][jt][r] *= al[r];
      bf16x8 pa = *(const bf16x8*)&P[wv][lm * 48 + 8 * lq];
#pragma unroll
      for (int jt = 0; jt < 4; jt++)
        Oa[qt][jt] = __builtin_amdgcn_mfma_f32_16x16x32_bf16(pa, vf[jt], Oa[qt][jt], 0, 0, 0);
    }
  }
  const int b = bh >> 4, h = bh & 15;
#pragma unroll
  for (int qt = 0; qt < 2; qt++) {
    float inv = 1.0f / lst[qt];
    float invl[4];
#pragma unroll
    for (int r = 0; r < 4; r++) invl[r] = __shfl(inv, 4 * lq + r);
#pragma unroll
    for (int r = 0; r < 4; r++) {
      int t = t0 + 16 * qt + 4 * lq + r;
#pragma unroll
      for (int jt = 0; jt < 4; jt++) {
        int c = h * 64 + 16 * jt + lm;
        Ob[((size_t)(b * T_ + t)) * 1024 + c] = f2bf(Oa[qt][jt][r] * invl[r]);
      }
    }
  }
}

extern "C" void kernel_launch(void* const* d_in, const int* in_sizes, int n_in,
                              void* d_out, int out_size, void* d_ws, size_t ws_size,
                              hipStream_t stream) {
  const float* x = (const float*)d_in[0];       // [4,2048,1024]
  const float* w_qkv = (const float*)d_in[1];   // [3072,1024]
  const float* w_out = (const float*)d_in[2];   // [1024,1024]
  float* out = (float*)d_out;                   // [4,2048,1024] fp32

  // workspace layout (bf16 = unsigned short), ~72 MB total
  unsigned short* xb = (unsigned short*)d_ws;                // 8192*1024 (reused as attn out)
  unsigned short* wqkvb = xb + (size_t)8192 * 1024;          // 3072*1024
  unsigned short* woutb = wqkvb + (size_t)3072 * 1024;       // 1024*1024
  unsigned short* qb = woutb + (size_t)1024 * 1024;          // 64*2048*64
  unsigned short* kb = qb + (size_t)64 * 2048 * 64;
  unsigned short* vb = kb + (size_t)64 * 2048 * 64;          // holds vt[B,H,D,T]

  cast_all<<<12288, 256, 0, stream>>>(x, w_qkv, w_out, xb, wqkvb, woutb);

  // qkv = x @ w_qkv^T -> q/k [B,H,T,D] + v transposed [B,H,D,T]
  gemm_qkv8<<<dim3(12, 32), 512, 0, stream>>>(xb, wqkvb, qb, kb, vb);

  // sliding-window attention -> [B,T,C] bf16 (aliases xb; dead after gemm_qkv)
  attn_swa<<<1024, 256, 0, stream>>>(qb, kb, vb, xb);

  // out = attn @ w_out^T (fp32 store)
  gemm_out<<<dim3(8, 64), 256, 0, stream>>>(xb, woutb, out);
}

// Round 10
// 204.958 us; speedup vs baseline: 1.0674x; 1.0674x over previous
//
#include <hip/hip_runtime.h>
#include <hip/hip_bf16.h>
#include <stdint.h>

typedef __attribute__((ext_vector_type(8))) short bf16x8;
typedef __attribute__((ext_vector_type(4))) float f32x4;
typedef __attribute__((ext_vector_type(4))) unsigned short u16x4;

#define B_ 4
#define T_ 2048
#define C_ 1024
#define H_ 16
#define D_ 64

// round-to-nearest-even fp32 -> bf16
__device__ __forceinline__ unsigned short f2bf(float f) {
  union { float f; uint32_t u; } v; v.f = f;
  uint32_t u = v.u;
  uint32_t r = (u + 0x7FFFu + ((u >> 16) & 1u)) >> 16;
  return (unsigned short)r;
}

// fused cast of all three fp32 inputs -> bf16 (one launch instead of three)
__global__ void __launch_bounds__(256) cast_all(const float* __restrict__ x,
                                                const float* __restrict__ wqkv,
                                                const float* __restrict__ wout,
                                                unsigned short* __restrict__ xb,
                                                unsigned short* __restrict__ wqkvb,
                                                unsigned short* __restrict__ woutb) {
  int bid = blockIdx.x;
  const float* src; unsigned short* dst; int i;
  if (bid < 8192)       { src = x;    dst = xb;    i = bid * 256 + threadIdx.x; }
  else if (bid < 11264) { src = wqkv; dst = wqkvb; i = (bid - 8192) * 256 + threadIdx.x; }
  else                  { src = wout; dst = woutb; i = (bid - 11264) * 256 + threadIdx.x; }
  float4 f = ((const float4*)src)[i];
  u16x4 o;
  o[0] = f2bf(f.x); o[1] = f2bf(f.y); o[2] = f2bf(f.z); o[3] = f2bf(f.w);
  ((u16x4*)dst)[i] = o;
}

// ---------------------------------------------------------------------------
// QKV GEMM: C[8192,3072] = A[8192,1024] * W[3072,1024]^T, bf16, fp32 acc.
// 128x128 tile, BK=32, 4 waves 2x2 (64x64 per wave, acc[4][4]) -- the
// measured-best structure (r3/r5: 73.8 us), with ONE change: QUAD-buffered
// LDS (4 slots x (A 8KB + B 8KB) = 64 KB), staging TWO K-tiles per barrier
// and computing TWO K-steps between barriers. Barrier count 32 -> 16 and the
// implicit vmcnt(0) drain at __syncthreads waits for loads issued ~2 compute
// steps earlier (2x the latency-hiding window). Targets the ~100 kcy/CU
// barrier-drain stall isolated by r1-r9 (MFMA 60 kcy + LDS 74 kcy measured,
// 180 kcy wall). LDS layout per slot stays the bank-optimal [*][32] (BK=64
// rows = 128B stride would be a 16-way conflict; gload_lds forbids swizzle).
// 64 KB -> 2 blocks/CU; grid 1536 = exactly 3 dispatch rounds (clean tail).
// Epilogue: Q/K -> LDS [128][132] transpose -> coalesced 16B scatter;
// V -> packed u16x4 to vt[B,H,D,T] (transposed for attn's PV vector load).
// ---------------------------------------------------------------------------
__global__ void __launch_bounds__(256) gemm_qkv(const unsigned short* __restrict__ A,
                                                const unsigned short* __restrict__ Bm,
                                                unsigned short* __restrict__ qb,
                                                unsigned short* __restrict__ kb,
                                                unsigned short* __restrict__ vb) {
  __shared__ short lds[32768];  // 64KB: A slots [0,16384) q*4096; B slots [16384,32768)
  const int tid = threadIdx.x;
  const int bm = blockIdx.y * 128;
  const int bn = blockIdx.x * 128;

  const int wave = tid >> 6;
  const int l = tid & 63;
  const int wm = wave >> 1, wn = wave & 1;
  const int lm = l & 15, lq = l >> 4;
  const int lr = l >> 2;           // row within 16-row staging chunk
  const int lc = (l & 3) << 3;     // k-col {0,8,16,24}

  f32x4 acc[4][4];
#pragma unroll
  for (int i = 0; i < 4; i++)
#pragma unroll
    for (int j = 0; j < 4; j++) acc[i][j] = (f32x4){0.f, 0.f, 0.f, 0.f};

  // staging: 16 chunks of 16 rows x 32 shorts per K-tile; waves 0-1 -> A, 2-3 -> B.
  const unsigned short* gsrc[4];
  int ldoff[4];
#pragma unroll
  for (int i = 0; i < 4; i++) {
    int c = wave * 4 + i;            // 0..15, wave-uniform
    if (c < 8) {
      gsrc[i] = A + (size_t)(bm + 16 * c + lr) * 1024 + lc;
      ldoff[i] = c * 512;                       // within A slot
    } else {
      gsrc[i] = Bm + (size_t)(bn + 16 * (c - 8) + lr) * 1024 + lc;
      ldoff[i] = 16384 + (c - 8) * 512;         // within B slot region
    }
  }

  // STAGE(q, kk): stage K-tile at col kk into slot q (0..3)
#define STAGE(q, kk)                                                             \
  do {                                                                           \
    _Pragma("unroll")                                                            \
    for (int i = 0; i < 4; i++) {                                                \
      __builtin_amdgcn_global_load_lds(                                          \
          (__attribute__((address_space(1))) void*)(uintptr_t)(const void*)(gsrc[i] + (kk)), \
          (__attribute__((address_space(3))) void*)(lds + ldoff[i] + (q) * 4096),            \
          16, 0, 0);                                                             \
    }                                                                            \
  } while (0)

  STAGE(0, 0);
  STAGE(1, 32);
  __syncthreads();  // prologue pair landed (vmcnt(0) drain) + visible

  for (int kk = 0; kk < 1024; kk += 64) {
    const int cp = (kk >> 6) & 1;              // current pair: {2cp, 2cp+1}
    if (kk + 64 < 1024) {                      // prefetch opposite pair
      STAGE(2 * (1 - cp), kk + 64);
      STAGE(2 * (1 - cp) + 1, kk + 96);
    }
#pragma unroll
    for (int sub = 0; sub < 2; sub++) {        // two K-steps, one barrier
      const int q = 2 * cp + sub;
      const short* As_ = lds + q * 4096;
      const short* Bs_ = lds + 16384 + q * 4096;
      bf16x8 af[4], bfr[4];
#pragma unroll
      for (int i = 0; i < 4; i++)
        af[i] = *(const bf16x8*)&As_[(wm * 64 + 16 * i + lm) * 32 + 8 * lq];
#pragma unroll
      for (int j = 0; j < 4; j++)
        bfr[j] = *(const bf16x8*)&Bs_[(wn * 64 + 16 * j + lm) * 32 + 8 * lq];
#pragma unroll
      for (int i = 0; i < 4; i++)
#pragma unroll
        for (int j = 0; j < 4; j++)
          acc[i][j] = __builtin_amdgcn_mfma_f32_16x16x32_bf16(af[i], bfr[j], acc[i][j], 0, 0, 0);
    }
    __syncthreads();  // prefetched pair drained + everyone done reading cur pair
  }
#undef STAGE

  // C/D layout: col = lane&15, row = (lane>>4)*4 + reg  [measured m89/m91]
  if (bn >= 2048) {
    // V block: store TRANSPOSED vt[b,h,d,t]; acc[.][.][0..3] = 4 consecutive t.
#pragma unroll
    for (int i = 0; i < 4; i++)
#pragma unroll
      for (int j = 0; j < 4; j++) {
        int m0 = bm + wm * 64 + 16 * i + 4 * lq;      // t base (4-aligned)
        int n = (bn - 2048) + wn * 64 + 16 * j + lm;  // 0..1023
        int h = n >> 6, d = n & 63;
        int b = m0 >> 11, t = m0 & 2047;
        u16x4 o;
#pragma unroll
        for (int r = 0; r < 4; r++) o[r] = f2bf(acc[i][j][r]);
        *(u16x4*)&vb[(((size_t)(b * 16 + h)) * 64 + d) * 2048 + t] = o;
      }
  } else {
    // Q/K block: LDS transpose [128][132] -> coalesced 16B stores
#pragma unroll
    for (int i = 0; i < 4; i++)
#pragma unroll
      for (int j = 0; j < 4; j++)
#pragma unroll
        for (int r = 0; r < 4; r++)
          lds[(wm * 64 + 16 * i + 4 * lq + r) * 132 + wn * 64 + 16 * j + lm] =
              (short)f2bf(acc[i][j][r]);
    __syncthreads();
#pragma unroll
    for (int k = 0; k < 8; k++) {
      int c = tid + 256 * k;
      int row = c >> 4;            // 0..127
      int col = (c & 15) << 3;     // 0..120
      bf16x8 v = *(const bf16x8*)&lds[row * 132 + col];
      int m = bm + row, n = bn + col;
      int which = n >> 10, rem = n & 1023;
      int h = rem >> 6, d = rem & 63;      // d 8-aligned, within one head
      int b = m >> 11, t = m & 2047;
      unsigned short* dst = (which == 0) ? qb : kb;
      *(bf16x8*)&dst[(((size_t)(b * 16 + h)) * 2048 + t) * 64 + d] = v;
    }
  }
}

// ---------------------------------------------------------------------------
// Out-proj GEMM: C[8192,1024] = A[8192,1024] * W[1024,1024]^T, fp32 out.
// Same quad-buffer transformation (16 barriers), 64 KB LDS, 2 blocks/CU;
// grid 512 = exactly 1 dispatch round.
// ---------------------------------------------------------------------------
__global__ void __launch_bounds__(256) gemm_out(const unsigned short* __restrict__ A,
                                                const unsigned short* __restrict__ Bm,
                                                float* __restrict__ fo) {
  __shared__ short lds[32768];
  const int tid = threadIdx.x;
  const int bm = blockIdx.y * 128;
  const int bn = blockIdx.x * 128;
  const int wave = tid >> 6;
  const int l = tid & 63;
  const int wm = wave >> 1, wn = wave & 1;
  const int lm = l & 15, lq = l >> 4;
  const int lr = l >> 2;
  const int lc = (l & 3) << 3;

  f32x4 acc[4][4];
#pragma unroll
  for (int i = 0; i < 4; i++)
#pragma unroll
    for (int j = 0; j < 4; j++) acc[i][j] = (f32x4){0.f, 0.f, 0.f, 0.f};

  const unsigned short* gsrc[4];
  int ldoff[4];
#pragma unroll
  for (int i = 0; i < 4; i++) {
    int c = wave * 4 + i;
    if (c < 8) {
      gsrc[i] = A + (size_t)(bm + 16 * c + lr) * 1024 + lc;
      ldoff[i] = c * 512;
    } else {
      gsrc[i] = Bm + (size_t)(bn + 16 * (c - 8) + lr) * 1024 + lc;
      ldoff[i] = 16384 + (c - 8) * 512;
    }
  }

#define STAGE(q, kk)                                                             \
  do {                                                                           \
    _Pragma("unroll")                                                            \
    for (int i = 0; i < 4; i++) {                                                \
      __builtin_amdgcn_global_load_lds(                                          \
          (__attribute__((address_space(1))) void*)(uintptr_t)(const void*)(gsrc[i] + (kk)), \
          (__attribute__((address_space(3))) void*)(lds + ldoff[i] + (q) * 4096),            \
          16, 0, 0);                                                             \
    }                                                                            \
  } while (0)

  STAGE(0, 0);
  STAGE(1, 32);
  __syncthreads();

  for (int kk = 0; kk < 1024; kk += 64) {
    const int cp = (kk >> 6) & 1;
    if (kk + 64 < 1024) {
      STAGE(2 * (1 - cp), kk + 64);
      STAGE(2 * (1 - cp) + 1, kk + 96);
    }
#pragma unroll
    for (int sub = 0; sub < 2; sub++) {
      const int q = 2 * cp + sub;
      const short* As_ = lds + q * 4096;
      const short* Bs_ = lds + 16384 + q * 4096;
      bf16x8 af[4], bfr[4];
#pragma unroll
      for (int i = 0; i < 4; i++)
        af[i] = *(const bf16x8*)&As_[(wm * 64 + 16 * i + lm) * 32 + 8 * lq];
#pragma unroll
      for (int j = 0; j < 4; j++)
        bfr[j] = *(const bf16x8*)&Bs_[(wn * 64 + 16 * j + lm) * 32 + 8 * lq];
#pragma unroll
      for (int i = 0; i < 4; i++)
#pragma unroll
        for (int j = 0; j < 4; j++)
          acc[i][j] = __builtin_amdgcn_mfma_f32_16x16x32_bf16(af[i], bfr[j], acc[i][j], 0, 0, 0);
    }
    __syncthreads();
  }
#undef STAGE

#pragma unroll
  for (int i = 0; i < 4; i++)
#pragma unroll
    for (int j = 0; j < 4; j++)
#pragma unroll
      for (int r = 0; r < 4; r++) {
        int m = bm + wm * 64 + 16 * i + 4 * lq + r;
        int n = bn + wn * 64 + 16 * j + lm;
        fo[(size_t)m * 1024 + n] = acc[i][j][r];
      }
}

// ---------------------------------------------------------------------------
// Sliding-window causal flash attention, SWAPPED-QK^T lane-local softmax.
// (unchanged from round 8 -- measured win)
// ---------------------------------------------------------------------------
__global__ void __launch_bounds__(256, 4) attn_swa(const unsigned short* __restrict__ Qb,
                                                   const unsigned short* __restrict__ Kb,
                                                   const unsigned short* __restrict__ Vt,
                                                   unsigned short* __restrict__ Ob) {
  __shared__ short P[4][16 * 48];  // per-wave P[q=16][k=32], row stride 48
  const int wv = threadIdx.x >> 6;
  const int l = threadIdx.x & 63;
  const int wid = blockIdx.x * 4 + wv;   // 0..4095
  const int bh = wid >> 6;               // 64 32-row q-groups per (b,h)
  const int t0 = (wid & 63) << 5;
  const int lm = l & 15, lq = l >> 4;
  const size_t base = (size_t)bh * (T_ * D_);

  bf16x8 qf[2][2];
#pragma unroll
  for (int qt = 0; qt < 2; qt++) {
    qf[qt][0] = *(const bf16x8*)(Qb + base + (size_t)(t0 + 16 * qt + lm) * 64 + 8 * lq);
    qf[qt][1] = *(const bf16x8*)(Qb + base + (size_t)(t0 + 16 * qt + lm) * 64 + 32 + 8 * lq);
  }

  float mst[2] = {-1e30f, -1e30f}, lst[2] = {0.f, 0.f};
  f32x4 Oa[2][4];
#pragma unroll
  for (int qt = 0; qt < 2; qt++)
#pragma unroll
    for (int jt = 0; jt < 4; jt++) Oa[qt][jt] = (f32x4){0.f, 0.f, 0.f, 0.f};

  const float cs = 0.125f * 1.44269504f;  // scale * log2(e)
  int jstart = t0 - 128; if (jstart < 0) jstart = 0;

  for (int j0 = jstart; j0 < t0 + 32; j0 += 32) {
    bf16x8 ka[2][2];
#pragma unroll
    for (int hh = 0; hh < 2; hh++) {
      int kr = j0 + 16 * hh + lm;
      ka[hh][0] = *(const bf16x8*)(Kb + base + (size_t)kr * 64 + 8 * lq);
      ka[hh][1] = *(const bf16x8*)(Kb + base + (size_t)kr * 64 + 32 + 8 * lq);
    }
    bf16x8 vf[4];
#pragma unroll
    for (int jt = 0; jt < 4; jt++)
      vf[jt] = *(const bf16x8*)(Vt + base + (size_t)(16 * jt + lm) * 2048 + j0 + 8 * lq);

#pragma unroll
    for (int qt = 0; qt < 2; qt++) {
      const int t0q = t0 + 16 * qt;
      const int t = t0q + lm;
      f32x4 s0 = (f32x4){0.f, 0.f, 0.f, 0.f}, s1 = (f32x4){0.f, 0.f, 0.f, 0.f};
      s0 = __builtin_amdgcn_mfma_f32_16x16x32_bf16(ka[0][0], qf[qt][0], s0, 0, 0, 0);
      s0 = __builtin_amdgcn_mfma_f32_16x16x32_bf16(ka[0][1], qf[qt][1], s0, 0, 0, 0);
      s1 = __builtin_amdgcn_mfma_f32_16x16x32_bf16(ka[1][0], qf[qt][0], s1, 0, 0, 0);
      s1 = __builtin_amdgcn_mfma_f32_16x16x32_bf16(ka[1][1], qf[qt][1], s1, 0, 0, 0);
      float sv[8];
      float m2 = -1e30f;
#pragma unroll
      for (int hh = 0; hh < 2; hh++)
#pragma unroll
        for (int r = 0; r < 4; r++) {
          int k = j0 + 16 * hh + 4 * lq + r;
          float x = (hh ? s1[r] : s0[r]) * cs;
          bool okm = (k <= t) && (k + 128 >= t);
          sv[hh * 4 + r] = okm ? x : -1e30f;
          m2 = fmaxf(m2, sv[hh * 4 + r]);
        }
      m2 = fmaxf(m2, __shfl_xor(m2, 16));
      m2 = fmaxf(m2, __shfl_xor(m2, 32));
      float mn = fmaxf(mst[qt], m2);
      float a = __builtin_amdgcn_exp2f(mst[qt] - mn);
      float ps = 0.f;
#pragma unroll
      for (int i = 0; i < 8; i++) {
        sv[i] = (sv[i] > -1e29f) ? __builtin_amdgcn_exp2f(sv[i] - mn) : 0.f;
        ps += sv[i];
      }
      ps += __shfl_xor(ps, 16);
      ps += __shfl_xor(ps, 32);
      lst[qt] = lst[qt] * a + ps;
      mst[qt] = mn;
#pragma unroll
      for (int hh = 0; hh < 2; hh++) {
        u16x4 pk;
#pragma unroll
        for (int r = 0; r < 4; r++) pk[r] = f2bf(sv[hh * 4 + r]);
        *(u16x4*)&P[wv][lm * 48 + 16 * hh + 4 * lq] = pk;
      }
      float al[4];
#pragma unroll
      for (int r = 0; r < 4; r++) al[r] = __shfl(a, 4 * lq + r);
#pragma unroll
      for (int jt = 0; jt < 4; jt++)
#pragma unroll
        for (int r = 0; r < 4; r++) Oa[qt][jt][r] *= al[r];
      bf16x8 pa = *(const bf16x8*)&P[wv][lm * 48 + 8 * lq];
#pragma unroll
      for (int jt = 0; jt < 4; jt++)
        Oa[qt][jt] = __builtin_amdgcn_mfma_f32_16x16x32_bf16(pa, vf[jt], Oa[qt][jt], 0, 0, 0);
    }
  }
  const int b = bh >> 4, h = bh & 15;
#pragma unroll
  for (int qt = 0; qt < 2; qt++) {
    float inv = 1.0f / lst[qt];
    float invl[4];
#pragma unroll
    for (int r = 0; r < 4; r++) invl[r] = __shfl(inv, 4 * lq + r);
#pragma unroll
    for (int r = 0; r < 4; r++) {
      int t = t0 + 16 * qt + 4 * lq + r;
#pragma unroll
      for (int jt = 0; jt < 4; jt++) {
        int c = h * 64 + 16 * jt + lm;
        Ob[((size_t)(b * T_ + t)) * 1024 + c] = f2bf(Oa[qt][jt][r] * invl[r]);
      }
    }
  }
}

extern "C" void kernel_launch(void* const* d_in, const int* in_sizes, int n_in,
                              void* d_out, int out_size, void* d_ws, size_t ws_size,
                              hipStream_t stream) {
  const float* x = (const float*)d_in[0];       // [4,2048,1024]
  const float* w_qkv = (const float*)d_in[1];   // [3072,1024]
  const float* w_out = (const float*)d_in[2];   // [1024,1024]
  float* out = (float*)d_out;                   // [4,2048,1024] fp32

  // workspace layout (bf16 = unsigned short), ~72 MB total
  unsigned short* xb = (unsigned short*)d_ws;                // 8192*1024 (reused as attn out)
  unsigned short* wqkvb = xb + (size_t)8192 * 1024;          // 3072*1024
  unsigned short* woutb = wqkvb + (size_t)3072 * 1024;       // 1024*1024
  unsigned short* qb = woutb + (size_t)1024 * 1024;          // 64*2048*64
  unsigned short* kb = qb + (size_t)64 * 2048 * 64;
  unsigned short* vb = kb + (size_t)64 * 2048 * 64;          // holds vt[B,H,D,T]

  cast_all<<<12288, 256, 0, stream>>>(x, w_qkv, w_out, xb, wqkvb, woutb);

  // qkv = x @ w_qkv^T -> q/k [B,H,T,D] + v transposed [B,H,D,T]
  gemm_qkv<<<dim3(24, 64), 256, 0, stream>>>(xb, wqkvb, qb, kb, vb);

  // sliding-window attention -> [B,T,C] bf16 (aliases xb; dead after gemm_qkv)
  attn_swa<<<1024, 256, 0, stream>>>(qb, kb, vb, xb);

  // out = attn @ w_out^T (fp32 store)
  gemm_out<<<dim3(8, 64), 256, 0, stream>>>(xb, woutb, out);
}